// Round 18
// baseline (890.880 us; speedup 1.0000x reference)
//
#include <hip/hip_runtime.h>

// GraphConv: edge MLP (384->256->640, bf16 MFMA) + slot-direct CSR pool + obj MLP (256->256->128)
// Round 18: r17 (BM=64, 80KB LDS, 2 blocks/CU, counted-vmcnt 3-buffer rotation) with the GEMM1
// A-schedule bug FIXED: A slice j+2 is loaded at odd stage s=2j+1 AFTER writeA consumes ap
// (consume-then-refill). Waits re-derived by FIFO token simulation (uniform VMCNT8, VMCNT4 tail).

using f32x4 = __attribute__((ext_vector_type(4))) float;
using s16x8 = __attribute__((ext_vector_type(8))) short;
typedef unsigned short u16x8 __attribute__((ext_vector_type(8)));

#define VMCNT0  asm volatile("s_waitcnt vmcnt(0)" ::: "memory")
#define VMCNT4  asm volatile("s_waitcnt vmcnt(4)" ::: "memory")
#define VMCNT8  asm volatile("s_waitcnt vmcnt(8)" ::: "memory")
#define VMCNT20 asm volatile("s_waitcnt vmcnt(20)" ::: "memory")
#define VMCNT36 asm volatile("s_waitcnt vmcnt(36)" ::: "memory")
#define LGKM0   asm volatile("s_waitcnt lgkmcnt(0)" ::: "memory")
#define BAR     __builtin_amdgcn_s_barrier()
#define SCHEDB  __builtin_amdgcn_sched_barrier(0)

static __device__ __forceinline__ unsigned short f2b(float f) {
    unsigned int u = __float_as_uint(f);
    unsigned int r = (u + 0x7fffu + ((u >> 16) & 1u)) >> 16;  // RNE f32->bf16
    return (unsigned short)r;
}

static __device__ __forceinline__ unsigned f2bpk(float lo, float hi) {
    unsigned r;
    asm("v_cvt_pk_bf16_f32 %0, %1, %2" : "=v"(r) : "v"(lo), "v"(hi));
    return r;
}

static __device__ __forceinline__ float b2f(unsigned short b) {
    return __uint_as_float(((unsigned)b) << 16);
}

static __device__ __forceinline__ unsigned swz(unsigned row, unsigned byteoff) {
    return byteoff ^ ((row & 7u) << 4);
}

static __device__ __forceinline__ void gload_lds16(const unsigned short* g, unsigned short* l) {
    __builtin_amdgcn_global_load_lds(
        (const __attribute__((address_space(1))) unsigned int*)g,
        (__attribute__((address_space(3))) unsigned int*)l,
        16, 0, 0);
}

#define PREP_ELEMS (98304 + 163840 + 65536 + 32768)   // 360448

// ---------------- fused weight prep + CSR count/slot ----------------
// w1aT: 12 tiles (kt) of [256c][32k] bf16 (16KB), byte=(c*64+kk*2)^((c&7)<<4)
// w1bT: 20 tiles (nc*4+kh) of [128c][64k] bf16 (16KB), byte=(c*128+kk*2)^((c&7)<<4)
__global__ void prep_count_kernel(const float* __restrict__ w1a, const float* __restrict__ w1b,
                                  const float* __restrict__ w2a, const float* __restrict__ w2b,
                                  unsigned short* __restrict__ w1aT, unsigned short* __restrict__ w1bT,
                                  unsigned short* __restrict__ w2aT, unsigned short* __restrict__ w2bT,
                                  const int* __restrict__ edges, int* __restrict__ cnt,
                                  int* __restrict__ slotS, int* __restrict__ slotO, int T) {
    int t = blockIdx.x * blockDim.x + threadIdx.x;
    if (t >= PREP_ELEMS) {
        int e = t - PREP_ELEMS;
        if (e < T) {
            slotS[e] = atomicAdd(&cnt[edges[2 * (long long)e]], 1);
            slotO[e] = atomicAdd(&cnt[edges[2 * (long long)e + 1]], 1);
        }
        return;
    }
    if (t < 12 * 8192) {
        int kt = t >> 13;
        int rem = t & 8191; int c = rem >> 5, kk = rem & 31;       // c 0..255, kk 0..31
        unsigned byte = ((unsigned)(c * 64 + kk * 2)) ^ ((c & 7u) << 4);
        *(unsigned short*)((char*)w1aT + (size_t)kt * 16384 + byte) =
            f2b(w1a[(size_t)(kt * 32 + kk) * 256 + c]);
        return;
    }
    t -= 98304;
    if (t < 20 * 8192) {
        int tile = t >> 13; int nc = tile >> 2, kh = tile & 3;
        int rem = t & 8191; int c = rem >> 6, kk = rem & 63;       // c 0..127, kk 0..63
        unsigned byte = ((unsigned)(c * 128 + kk * 2)) ^ ((c & 7u) << 4);
        *(unsigned short*)((char*)w1bT + (size_t)tile * 16384 + byte) =
            f2b(w1b[(size_t)(kh * 64 + kk) * 640 + nc * 128 + c]);
        return;
    }
    t -= 163840;
    if (t < 65536) { int n = t >> 8, k = t & 255; w2aT[t] = f2b(w2a[k * 256 + n]); return; }
    t -= 65536;
    if (t < 32768) { int n = t >> 8, k = t & 255; w2bT[t] = f2b(w2b[k * 128 + n]); return; }
}

__global__ void scan_kernel(const int* __restrict__ cnt, int* __restrict__ rowptr, int O) {
    __shared__ int sc[1024];
    const int tid = threadIdx.x;
    const int per = (O + 1023) >> 10;
    const int base = tid * per;
    int s = 0;
    for (int i = 0; i < per; ++i) { int j = base + i; if (j < O) s += cnt[j]; }
    sc[tid] = s;
    __syncthreads();
    for (int d = 1; d < 1024; d <<= 1) {
        int v = (tid >= d) ? sc[tid - d] : 0;
        __syncthreads();
        sc[tid] += v;
        __syncthreads();
    }
    int off = sc[tid] - s;
    for (int i = 0; i < per; ++i) {
        int j = base + i;
        if (j < O) { rowptr[j] = off; off += cnt[j]; }
    }
    if (tid == 0) rowptr[O] = sc[1023];
}

// ---------------- edge MLP: BM=64, 256 thr (4 waves), 80KB LDS, 2 blocks/CU ----------------
__global__ __launch_bounds__(256, 2) void edge_mlp(
    const float* __restrict__ obj, const float* __restrict__ pred,
    const int* __restrict__ edges,
    const unsigned short* __restrict__ w1aT, const float* __restrict__ b1a,
    const unsigned short* __restrict__ w1bT, const float* __restrict__ b1b,
    const int* __restrict__ slotS, const int* __restrict__ slotO,
    const int* __restrict__ rowptr,
    unsigned short* __restrict__ edgeout, float* __restrict__ outP, int T) {
    const int m0 = blockIdx.x * 64;
    const int tid = threadIdx.x;
    const int lane = tid & 63, wid = tid >> 6;      // 4 waves
    const int wn = wid;                              // col slice
    const bool evenL = ((lane & 1) == 0);

    // LDS 80 KB: [0,32K) H[64][256] swz (A dbuf 2x8KB unioned at [0,16K));
    //            [32K,80K) three 16KB B buffers, rotation idx s%3
    __shared__ unsigned short U[40960];
    char* const ldsb = (char*)U;
    char* const bbase = ldsb + 32768;

    bool okR[4][4];
    #pragma unroll
    for (int mi = 0; mi < 4; ++mi)
        #pragma unroll
        for (int rr = 0; rr < 4; ++rr)
            okR[mi][rr] = (m0 + mi * 16 + ((lane >> 4) << 2) + rr) < T;

    // global CSR slots = local slot + rowptr[node]
    int slotSr[4][2], slotOr[4][2];
    #pragma unroll
    for (int mi = 0; mi < 4; ++mi)
        #pragma unroll
        for (int k = 0; k < 2; ++k) {
            int rsel = evenL ? k : 2 + k;
            int e = m0 + mi * 16 + ((lane >> 4) << 2) + rsel;
            if (e >= T) e = T - 1;
            int si = edges[2 * (long long)e];
            int oi = edges[2 * (long long)e + 1];
            slotSr[mi][k] = slotS[e] + rowptr[si];
            slotOr[mi][k] = slotO[e] + rowptr[oi];
        }

    const int r = tid >> 2;   // staging row 0..63
    const int q = tid & 3;
    int e_r = m0 + r; if (e_r >= T) e_r = T - 1;
    const int sIdx_r = edges[2 * (long long)e_r];
    const int oIdx_r = edges[2 * (long long)e_r + 1];

    float bias1[4], bias2[5][2];
    #pragma unroll
    for (int nj = 0; nj < 4; ++nj) bias1[nj] = b1a[wn * 64 + nj * 16 + (lane & 15)];
    #pragma unroll
    for (int nc = 0; nc < 5; ++nc)
        #pragma unroll
        for (int nj = 0; nj < 2; ++nj)
            bias2[nc][nj] = b1b[nc * 128 + wn * 32 + nj * 16 + (lane & 15)];

    // force-retire ALL preamble vmem loads: clean vmcnt FIFO before the counted pipeline
    #pragma unroll
    for (int mi = 0; mi < 4; ++mi)
        #pragma unroll
        for (int k = 0; k < 2; ++k)
            asm volatile("" :: "v"(slotSr[mi][k]), "v"(slotOr[mi][k]));
    #pragma unroll
    for (int nj = 0; nj < 4; ++nj) asm volatile("" :: "v"(bias1[nj]));
    #pragma unroll
    for (int nc = 0; nc < 5; ++nc)
        #pragma unroll
        for (int nj = 0; nj < 2; ++nj) asm volatile("" :: "v"(bias2[nc][nj]));
    asm volatile("" :: "v"((float)sIdx_r), "v"((float)oIdx_r));
    SCHEDB;

    // A slice j (j=0..5): 64 rows x 64 k, k-global = j*64
    auto aSrc = [&](int j) -> const float4* {
        const float* s;
        if (j < 2)      s = obj  + (long long)sIdx_r * 128 + j * 64;
        else if (j < 4) s = pred + (long long)e_r   * 128 + (j - 2) * 64;
        else            s = obj  + (long long)oIdx_r * 128 + (j - 4) * 64;
        return (const float4*)s;
    };

    // unified tile pointer: 0..11 = w1aT tiles, 12..31 = w1bT tiles (16KB each)
    auto tp = [&](int i) -> const unsigned short* {
        return (i < 12) ? (w1aT + (size_t)i * 8192) : (w1bT + (size_t)(i - 12) * 8192);
    };

    auto stage16 = [&](const unsigned short* gt, char* bb) {
        #pragma unroll
        for (int rr4 = 0; rr4 < 4; ++rr4) {
            unsigned off = wid * 4096u + rr4 * 1024u;
            gload_lds16((const unsigned short*)((const char*)gt + off + lane * 16u),
                        (unsigned short*)(bb + off));
        }
    };

    auto writeA = [&](const float4* ap, char* ab) {
        #pragma unroll
        for (int i = 0; i < 4; ++i) {
            float4 v = ap[i];
            uint2 pk;
            pk.x = f2bpk(v.x, v.y);
            pk.y = f2bpk(v.z, v.w);
            unsigned byte = (r * 128u + q * 32u + i * 8u) ^ ((r & 7u) << 4);
            *(uint2*)(ab + byte) = pk;
        }
    };

    f32x4 acc1[4][4];
    #pragma unroll
    for (int a = 0; a < 4; ++a)
        #pragma unroll
        for (int b = 0; b < 4; ++b) acc1[a][b] = f32x4{0.f, 0.f, 0.f, 0.f};

    // GEMM1 stage: A slice [64r][64k] stride 128B at koff; B tile [256c][32k] stride 64B
    auto mfma1 = [&](const char* ab, const char* bb, unsigned koff) {
        const unsigned kkA = koff + ((lane >> 4) << 3);
        const unsigned kkB = ((lane >> 4) << 3);
        s16x8 af[4];
        #pragma unroll
        for (int mi = 0; mi < 4; ++mi) {
            unsigned row = mi * 16u + (lane & 15);
            af[mi] = *(const s16x8*)(ab + ((row * 128u + kkA * 2u) ^ ((row & 7u) << 4)));
        }
        #pragma unroll
        for (int nj = 0; nj < 4; ++nj) {
            unsigned c = wn * 64u + nj * 16u + (lane & 15);
            s16x8 bf = *(const s16x8*)(bb + ((c * 64u + kkB * 2u) ^ ((c & 7u) << 4)));
            #pragma unroll
            for (int mi = 0; mi < 4; ++mi)
                acc1[mi][nj] = __builtin_amdgcn_mfma_f32_16x16x32_bf16(af[mi], bf, acc1[mi][nj], 0, 0, 0);
        }
    };

    // ---- prologue: A0->abuf0; B0,B1 in flight; A1 in flight ----
    float4 ap[4];
    {
        const float4* s4 = aSrc(0);
        #pragma unroll
        for (int i = 0; i < 4; ++i) ap[i] = s4[q * 4 + i];
    }
    writeA(ap, ldsb);                      // compiler drains A0
    stage16(tp(0), bbase);                 // B0 (+4)
    stage16(tp(1), bbase + 16384);         // B1 (+4)
    {
        const float4* s4 = aSrc(1);
        #pragma unroll
        for (int i = 0; i < 4; ++i) ap[i] = s4[q * 4 + i];   // A1 (+4)
    }
    VMCNT8;                                // drains B0; B1+A1 fly
    LGKM0; BAR; SCHEDB;

    // ---- GEMM1 stages s=0..11: consume-then-refill A schedule (FIXED) ----
    // slice j=s>>1 computed at stages 2j,2j+1 from abuf[j&1]; writeA(A(j+1)) at odd stage 2j+1
    // AFTER draining it; A(j+2) loaded right after (ap free). Waits per token simulation.
    #pragma unroll
    for (int s = 0; s < 12; ++s) {
        stage16(tp(s + 2), bbase + ((s + 2) % 3) * 16384);   // +4 (B(s+2))
        __builtin_amdgcn_s_setprio(1);
        mfma1(ldsb + ((s >> 1) & 1) * 8192, bbase + (s % 3) * 16384, (s & 1) * 32u);
        __builtin_amdgcn_s_setprio(0);
        if ((s & 1) == 1 && s <= 9) {
            VMCNT8;                                          // drain A slice (s>>1)+1 (oldest)
            writeA(ap, ldsb + (((s >> 1) + 1) & 1) * 8192);
            if (s <= 7) {
                const float4* s4 = aSrc((s >> 1) + 2);       // +4 (A slice j+2)
                #pragma unroll
                for (int i = 0; i < 4; ++i) ap[i] = s4[q * 4 + i];
                VMCNT8;                                      // drain B(s+1); keep B(s+2)+A_next
            } else {
                VMCNT4;                                      // s==9: keep B(s+2) only
            }
        } else {
            if (s <= 8) { VMCNT8; }                          // keep pending A + B(s+2)
            else        { VMCNT4; }                          // s=10,11: keep B(s+2) only
        }
        LGKM0; BAR; SCHEDB;
    }

    // ---- transition: H = relu(acc1+b1a) -> [64][256] swz over [0,32K); B13 in flight ----
    #pragma unroll
    for (int nj = 0; nj < 4; ++nj) {
        unsigned col = wn * 64u + nj * 16u + (lane & 15);
        #pragma unroll
        for (int mi = 0; mi < 4; ++mi) {
            float r0 = fmaxf(acc1[mi][nj][0] + bias1[nj], 0.f);
            float r1 = fmaxf(acc1[mi][nj][1] + bias1[nj], 0.f);
            float r2 = fmaxf(acc1[mi][nj][2] + bias1[nj], 0.f);
            float r3 = fmaxf(acc1[mi][nj][3] + bias1[nj], 0.f);
            unsigned p01 = f2bpk(r0, r1);
            unsigned p23 = f2bpk(r2, r3);
            unsigned rowb = mi * 16u + ((lane >> 4) << 2);
            *(unsigned short*)(ldsb + ((rowb * 512u + col * 2u) ^ ((rowb & 7u) << 4))) = (unsigned short)p01;
            *(unsigned short*)(ldsb + (((rowb + 1) * 512u + col * 2u) ^ (((rowb + 1) & 7u) << 4))) = (unsigned short)(p01 >> 16);
            *(unsigned short*)(ldsb + (((rowb + 2) * 512u + col * 2u) ^ (((rowb + 2) & 7u) << 4))) = (unsigned short)p23;
            *(unsigned short*)(ldsb + (((rowb + 3) * 512u + col * 2u) ^ (((rowb + 3) & 7u) << 4))) = (unsigned short)(p23 >> 16);
        }
    }
    LGKM0; BAR; SCHEDB;

    // ---- GEMM2 stages s=12..31 (tile s; nc=(s-12)>>2, kh=(s-12)&3) ----
    f32x4 acc2[4][2];
    #pragma unroll
    for (int s = 12; s < 32; ++s) {
        const int nc = (s - 12) >> 2;
        const int kh = (s - 12) & 3;
        if (kh == 0) {
            #pragma unroll
            for (int a = 0; a < 4; ++a)
                #pragma unroll
                for (int b = 0; b < 2; ++b) acc2[a][b] = f32x4{0.f, 0.f, 0.f, 0.f};
        }
        if (s + 2 <= 31) stage16(tp(s + 2), bbase + ((s + 2) % 3) * 16384);   // +4
        const char* bb = bbase + (s % 3) * 16384;
        __builtin_amdgcn_s_setprio(1);
        #pragma unroll
        for (int ks = 0; ks < 2; ++ks) {
            const unsigned kkB = ks * 32u + ((lane >> 4) << 3);
            const unsigned kkH = kh * 64u + kkB;
            s16x8 af[4];
            #pragma unroll
            for (int mi = 0; mi < 4; ++mi) {
                unsigned row = mi * 16u + (lane & 15);
                af[mi] = *(const s16x8*)(ldsb + ((row * 512u + kkH * 2u) ^ ((row & 7u) << 4)));
            }
            #pragma unroll
            for (int nj = 0; nj < 2; ++nj) {
                unsigned c = wn * 32u + nj * 16u + (lane & 15);
                s16x8 bf = *(const s16x8*)(bb + ((c * 128u + kkB * 2u) ^ ((c & 7u) << 4)));
                #pragma unroll
                for (int mi = 0; mi < 4; ++mi)
                    acc2[mi][nj] = __builtin_amdgcn_mfma_f32_16x16x32_bf16(af[mi], bf, acc2[mi][nj], 0, 0, 0);
            }
        }
        __builtin_amdgcn_s_setprio(0);

        // epilogue at kh==3 (stores newest in FIFO, counted through)
        if (kh == 3) {
            if (nc == 2) {
                #pragma unroll
                for (int nj = 0; nj < 2; ++nj) {
                    int col = 2 * 128 + wn * 32 + nj * 16 + (lane & 15);
                    #pragma unroll
                    for (int mi = 0; mi < 4; ++mi)
                        #pragma unroll
                        for (int rr = 0; rr < 4; ++rr) {
                            int row = mi * 16 + ((lane >> 4) << 2) + rr;
                            if (okR[mi][rr]) {
                                float v = acc2[mi][nj][rr] + bias2[2][nj];
                                v = v > 0.f ? v : 0.f;
                                outP[(long long)(m0 + row) * 128 + (col - 256)] = v;   // +32
                            }
                        }
                }
            } else {
                #pragma unroll
                for (int nj = 0; nj < 2; ++nj) {
                    int col = nc * 128 + wn * 32 + nj * 16 + (lane & 15);
                    int pc = (nc < 2) ? col : (col - 384);
                    int pcb = (lane & 1) ? (pc - 1) : pc;
                    #pragma unroll
                    for (int mi = 0; mi < 4; ++mi) {
                        float vv[4];
                        #pragma unroll
                        for (int rr = 0; rr < 4; ++rr) {
                            float v = acc2[mi][nj][rr] + bias2[nc][nj];
                            vv[rr] = v > 0.f ? v : 0.f;
                        }
                        float nb0 = __shfl_xor(vv[0], 1);
                        float nb1 = __shfl_xor(vv[1], 1);
                        float nb2 = __shfl_xor(vv[2], 1);
                        float nb3 = __shfl_xor(vv[3], 1);
                        #pragma unroll
                        for (int k = 0; k < 2; ++k) {
                            float lo = evenL ? (k ? vv[1] : vv[0]) : (k ? nb3 : nb2);
                            float hi = evenL ? (k ? nb1 : nb0) : (k ? vv[3] : vv[2]);
                            int rsel = evenL ? k : 2 + k;
                            if (okR[mi][rsel]) {
                                int slot = (nc < 2) ? slotSr[mi][k] : slotOr[mi][k];
                                unsigned pk = f2bpk(lo, hi);
                                *(unsigned*)(edgeout + (size_t)slot * 256 + pcb) = pk;  // +16
                            }
                        }
                    }
                }
            }
        }

        // stage-end wait per FIFO token simulation (s=31: none, endpgm)
        if (s < 31) {
            if (s == 30)                                           { VMCNT0; }
            else if (s == 15 || s == 16 || s == 19 || s == 20 ||
                     s == 27 || s == 28)                           { VMCNT20; }
            else if (s == 23 || s == 24)                           { VMCNT36; }
            else                                                   { VMCNT4; }
            LGKM0; BAR; SCHEDB;
        }
    }
}

// ---------------- object MLP with fused CSR-gather staging ----------------
__global__ __launch_bounds__(256, 3) void obj_mlp(
    const unsigned short* __restrict__ edgeout, const int* __restrict__ rowptr,
    const unsigned short* __restrict__ w2aT, const float* __restrict__ b2a,
    const unsigned short* __restrict__ w2bT, const float* __restrict__ b2b,
    float* __restrict__ outObj, int O) {
    const int m0 = blockIdx.x * 64;
    const int tid = threadIdx.x;
    const int lane = tid & 63, wid = tid >> 6;
    const int wm = wid >> 1, wn = wid & 1;

    __shared__ unsigned short Abuf[64 * 256];

    for (int it = 0; it < 16; ++it) {
        const int row = it * 4 + wid;
        const int oI = m0 + row;
        float ax = 0.f, ay = 0.f, az = 0.f, aw = 0.f;
        float bx = 0.f, by = 0.f, bz = 0.f, bw = 0.f;
        int n = 0;
        if (oI < O) {
            const int beg = rowptr[oI];
            n = rowptr[oI + 1] - beg;
            const unsigned short* base = edgeout + (size_t)beg * 256 + lane * 4;
            int i = 0;
            for (; i + 7 < n; i += 8) {
                ushort4 v0 = *(const ushort4*)(base + (size_t)(i    ) * 256);
                ushort4 v1 = *(const ushort4*)(base + (size_t)(i + 1) * 256);
                ushort4 v2 = *(const ushort4*)(base + (size_t)(i + 2) * 256);
                ushort4 v3 = *(const ushort4*)(base + (size_t)(i + 3) * 256);
                ushort4 v4 = *(const ushort4*)(base + (size_t)(i + 4) * 256);
                ushort4 v5 = *(const ushort4*)(base + (size_t)(i + 5) * 256);
                ushort4 v6 = *(const ushort4*)(base + (size_t)(i + 6) * 256);
                ushort4 v7 = *(const ushort4*)(base + (size_t)(i + 7) * 256);
                ax += b2f(v0.x); ay += b2f(v0.y); az += b2f(v0.z); aw += b2f(v0.w);
                bx += b2f(v1.x); by += b2f(v1.y); bz += b2f(v1.z); bw += b2f(v1.w);
                ax += b2f(v2.x); ay += b2f(v2.y); az += b2f(v2.z); aw += b2f(v2.w);
                bx += b2f(v3.x); by += b2f(v3.y); bz += b2f(v3.z); bw += b2f(v3.w);
                ax += b2f(v4.x); ay += b2f(v4.y); az += b2f(v4.z); aw += b2f(v4.w);
                bx += b2f(v5.x); by += b2f(v5.y); bz += b2f(v5.z); bw += b2f(v5.w);
                ax += b2f(v6.x); ay += b2f(v6.y); az += b2f(v6.z); aw += b2f(v6.w);
                bx += b2f(v7.x); by += b2f(v7.y); bz += b2f(v7.z); bw += b2f(v7.w);
            }
            for (; i < n; ++i) {
                ushort4 v0 = *(const ushort4*)(base + (size_t)i * 256);
                ax += b2f(v0.x); ay += b2f(v0.y); az += b2f(v0.z); aw += b2f(v0.w);
            }
        }
        float inv = 1.f / fmaxf((float)n, 1.f);
        uint2 pk;
        pk.x = f2bpk((ax + bx) * inv, (ay + by) * inv);
        pk.y = f2bpk((az + bz) * inv, (aw + bw) * inv);
        unsigned byte = ((unsigned)row * 512u + (unsigned)lane * 8u) ^ (((unsigned)row & 7u) << 4);
        *(uint2*)((char*)Abuf + byte) = pk;
    }
    __syncthreads();

    f32x4 acc1[2][2][4];
    #pragma unroll
    for (int a = 0; a < 2; ++a)
        #pragma unroll
        for (int b = 0; b < 2; ++b)
            #pragma unroll
            for (int c = 0; c < 4; ++c) acc1[a][b][c] = f32x4{0.f, 0.f, 0.f, 0.f};
    #pragma unroll
    for (int ks = 0; ks < 8; ++ks) {
        const int klane = ks * 32 + ((lane >> 4) << 3);
        s16x8 af[2];
        #pragma unroll
        for (int mi = 0; mi < 2; ++mi) {
            int row = wm * 32 + mi * 16 + (lane & 15);
            af[mi] = *(const s16x8*)((const char*)Abuf + swz(row, row * 512u + klane * 2u));
        }
        #pragma unroll
        for (int nb = 0; nb < 2; ++nb)
            #pragma unroll
            for (int nj = 0; nj < 4; ++nj) {
                int col = nb * 128 + wn * 64 + nj * 16 + (lane & 15);
                s16x8 bf = *(const s16x8*)(w2aT + (long long)col * 256 + klane);
                #pragma unroll
                for (int mi = 0; mi < 2; ++mi)
                    acc1[nb][mi][nj] = __builtin_amdgcn_mfma_f32_16x16x32_bf16(af[mi], bf, acc1[nb][mi][nj], 0, 0, 0);
            }
    }
    __syncthreads();

    #pragma unroll
    for (int nb = 0; nb < 2; ++nb)
        #pragma unroll
        for (int nj = 0; nj < 4; ++nj) {
            int col = nb * 128 + wn * 64 + nj * 16 + (lane & 15);
            float bias = b2a[col];
            #pragma unroll
            for (int mi = 0; mi < 2; ++mi) {
                float r0 = fmaxf(acc1[nb][mi][nj][0] + bias, 0.f);
                float r1 = fmaxf(acc1[nb][mi][nj][1] + bias, 0.f);
                float r2 = fmaxf(acc1[nb][mi][nj][2] + bias, 0.f);
                float r3 = fmaxf(acc1[nb][mi][nj][3] + bias, 0.f);
                unsigned p01 = f2bpk(r0, r1);
                unsigned p23 = f2bpk(r2, r3);
                int rowb = wm * 32 + mi * 16 + ((lane >> 4) << 2);
                *(unsigned short*)((char*)Abuf + swz(rowb, rowb * 512u + col * 2u)) = (unsigned short)p01;
                *(unsigned short*)((char*)Abuf + swz(rowb + 1, (rowb + 1) * 512u + col * 2u)) = (unsigned short)(p01 >> 16);
                *(unsigned short*)((char*)Abuf + swz(rowb + 2, (rowb + 2) * 512u + col * 2u)) = (unsigned short)p23;
                *(unsigned short*)((char*)Abuf + swz(rowb + 3, (rowb + 3) * 512u + col * 2u)) = (unsigned short)(p23 >> 16);
            }
        }
    __syncthreads();

    f32x4 acc2[2][4];
    #pragma unroll
    for (int b = 0; b < 2; ++b)
        #pragma unroll
        for (int c = 0; c < 4; ++c) acc2[b][c] = f32x4{0.f, 0.f, 0.f, 0.f};
    #pragma unroll
    for (int ks = 0; ks < 8; ++ks) {
        const int klane = ks * 32 + ((lane >> 4) << 3);
        s16x8 af[2];
        #pragma unroll
        for (int mi = 0; mi < 2; ++mi) {
            int row = wm * 32 + mi * 16 + (lane & 15);
            af[mi] = *(const s16x8*)((const char*)Abuf + swz(row, row * 512u + klane * 2u));
        }
        #pragma unroll
        for (int nj = 0; nj < 4; ++nj) {
            int col = wn * 64 + nj * 16 + (lane & 15);
            s16x8 bf = *(const s16x8*)(w2bT + (long long)col * 256 + klane);
            #pragma unroll
            for (int mi = 0; mi < 2; ++mi)
                acc2[mi][nj] = __builtin_amdgcn_mfma_f32_16x16x32_bf16(af[mi], bf, acc2[mi][nj], 0, 0, 0);
        }
    }

    #pragma unroll
    for (int nj = 0; nj < 4; ++nj) {
        int col = wn * 64 + nj * 16 + (lane & 15);
        float bias = b2b[col];
        #pragma unroll
        for (int mi = 0; mi < 2; ++mi)
            #pragma unroll
            for (int rr = 0; rr < 4; ++rr) {
                int row = wm * 32 + mi * 16 + ((lane >> 4) << 2) + rr;
                int o = m0 + row;
                if (o < O) {
                    float v = acc2[mi][nj][rr] + bias;
                    v = v > 0.f ? v : 0.f;
                    outObj[(long long)o * 128 + col] = v;
                }
            }
    }
}

extern "C" void kernel_launch(void* const* d_in, const int* in_sizes, int n_in,
                              void* d_out, int out_size, void* d_ws, size_t ws_size,
                              hipStream_t stream) {
    const float* obj  = (const float*)d_in[0];
    const float* pred = (const float*)d_in[1];
    const int*   edges = (const int*)d_in[2];
    const float* w1a = (const float*)d_in[3];
    const float* b1a = (const float*)d_in[4];
    const float* w1b = (const float*)d_in[5];
    const float* b1b = (const float*)d_in[6];
    const float* w2a = (const float*)d_in[7];
    const float* b2a = (const float*)d_in[8];
    const float* w2b = (const float*)d_in[9];
    const float* b2b = (const float*)d_in[10];

    const int O = in_sizes[0] / 128;
    const int T = in_sizes[1] / 128;

    auto al = [](size_t x) { return (x + 255) & ~(size_t)255; };
    const size_t szEdgeout = (size_t)2 * T * 256 * 2;
    const size_t szCnt     = (size_t)O * 4;
    const size_t szRow     = (size_t)(O + 1) * 4;
    const size_t szSlot    = (size_t)T * 4;

    size_t off = 0;
    char* ws = (char*)d_ws;
    unsigned short* edgeout = (unsigned short*)(ws + off); off += al(szEdgeout);
    int* cnt    = (int*)(ws + off); off += al(szCnt);
    int* rowptr = (int*)(ws + off); off += al(szRow);
    int* slotS  = (int*)(ws + off); off += al(szSlot);
    int* slotO  = (int*)(ws + off); off += al(szSlot);
    unsigned short* w1aT = (unsigned short*)(ws + off); off += (size_t)12 * 8192 * 2;    // 192 KB
    unsigned short* w1bT = (unsigned short*)(ws + off); off += (size_t)20 * 8192 * 2;    // 320 KB
    unsigned short* w2aT = (unsigned short*)(ws + off); off += (size_t)256 * 256 * 2;
    unsigned short* w2bT = (unsigned short*)(ws + off);

    float* outObj = (float*)d_out;
    float* outP   = (float*)d_out + (size_t)O * 128;

    hipMemsetAsync(cnt, 0, szCnt, stream);
    const int totalT = PREP_ELEMS + T;
    prep_count_kernel<<<(totalT + 255) / 256, 256, 0, stream>>>(
        w1a, w1b, w2a, w2b, w1aT, w1bT, w2aT, w2bT, edges, cnt, slotS, slotO, T);
    scan_kernel<<<1, 1024, 0, stream>>>(cnt, rowptr, O);
    edge_mlp<<<(T + 63) / 64, 256, 0, stream>>>(obj, pred, edges, w1aT, b1a, w1bT, b1b,
                                                slotS, slotO, rowptr, edgeout, outP, T);
    obj_mlp<<<(O + 63) / 64, 256, 0, stream>>>(edgeout, rowptr, w2aT, b2a, w2bT, b2b, outObj, O);
}

// Round 19
// 868.052 us; speedup vs baseline: 1.0263x; 1.0263x over previous
//
#include <hip/hip_runtime.h>

// GraphConv: edge MLP (384->256->640, bf16 MFMA) + slot-direct CSR pool + obj MLP (256->256->128)
// Round 19: edge_mlp reverted to round-16 (best measured: 555us). obj_mlp gather upgraded to
// PAIRED 16B loads: CSR rows are contiguous, so each wave reads 2 rows (1024B) per load round
// (lane half 0 = even rows, half 1 = odd rows), combined via one shfl_xor(32) per column.

using f32x4 = __attribute__((ext_vector_type(4))) float;
using s16x8 = __attribute__((ext_vector_type(8))) short;
typedef unsigned short u16x8 __attribute__((ext_vector_type(8)));

#define VMCNT4  asm volatile("s_waitcnt vmcnt(4)" ::: "memory")
#define VMCNT8  asm volatile("s_waitcnt vmcnt(8)" ::: "memory")
#define VMCNT16 asm volatile("s_waitcnt vmcnt(16)" ::: "memory")
#define VMCNT20 asm volatile("s_waitcnt vmcnt(20)" ::: "memory")
#define VMCNT36 asm volatile("s_waitcnt vmcnt(36)" ::: "memory")
#define LGKM0   asm volatile("s_waitcnt lgkmcnt(0)" ::: "memory")
#define BAR     __builtin_amdgcn_s_barrier()
#define SCHEDB  __builtin_amdgcn_sched_barrier(0)

static __device__ __forceinline__ unsigned short f2b(float f) {
    unsigned int u = __float_as_uint(f);
    unsigned int r = (u + 0x7fffu + ((u >> 16) & 1u)) >> 16;  // RNE f32->bf16
    return (unsigned short)r;
}

static __device__ __forceinline__ unsigned f2bpk(float lo, float hi) {
    unsigned r;
    asm("v_cvt_pk_bf16_f32 %0, %1, %2" : "=v"(r) : "v"(lo), "v"(hi));
    return r;
}

static __device__ __forceinline__ float b2f(unsigned short b) {
    return __uint_as_float(((unsigned)b) << 16);
}

static __device__ __forceinline__ unsigned swz(unsigned row, unsigned byteoff) {
    return byteoff ^ ((row & 7u) << 4);
}

static __device__ __forceinline__ void gload_lds16(const unsigned short* g, unsigned short* l) {
    __builtin_amdgcn_global_load_lds(
        (const __attribute__((address_space(1))) unsigned int*)g,
        (__attribute__((address_space(3))) unsigned int*)l,
        16, 0, 0);
}

#define PREP_ELEMS (98304 + 163840 + 65536 + 32768)   // 360448

// ---------------- fused weight prep + CSR count/slot (round-16 tiling) ----------------
// w1aT: 6 tiles [256c][64k] (32KB), byte=(c*128+kk*2)^((c&7)<<4)
// w1bT: 10 tiles [128c][128k] (32KB), byte=(c*256+kk*2)^((c&7)<<4)
__global__ void prep_count_kernel(const float* __restrict__ w1a, const float* __restrict__ w1b,
                                  const float* __restrict__ w2a, const float* __restrict__ w2b,
                                  unsigned short* __restrict__ w1aT, unsigned short* __restrict__ w1bT,
                                  unsigned short* __restrict__ w2aT, unsigned short* __restrict__ w2bT,
                                  const int* __restrict__ edges, int* __restrict__ cnt,
                                  int* __restrict__ slotS, int* __restrict__ slotO, int T) {
    int t = blockIdx.x * blockDim.x + threadIdx.x;
    if (t >= PREP_ELEMS) {
        int e = t - PREP_ELEMS;
        if (e < T) {
            slotS[e] = atomicAdd(&cnt[edges[2 * (long long)e]], 1);
            slotO[e] = atomicAdd(&cnt[edges[2 * (long long)e + 1]], 1);
        }
        return;
    }
    if (t < 6 * 16384) {
        int kt = t >> 14;
        int rem = t & 16383; int c = rem >> 6, kk = rem & 63;
        unsigned byte = ((unsigned)(c * 128 + kk * 2)) ^ ((c & 7u) << 4);
        *(unsigned short*)((char*)w1aT + (size_t)kt * 32768 + byte) =
            f2b(w1a[(size_t)(kt * 64 + kk) * 256 + c]);
        return;
    }
    t -= 98304;
    if (t < 10 * 16384) {
        int tile = t >> 14; int nc = tile >> 1, kh = tile & 1;
        int rem = t & 16383; int c = rem >> 7, kk = rem & 127;
        unsigned byte = ((unsigned)(c * 256 + kk * 2)) ^ ((c & 7u) << 4);
        *(unsigned short*)((char*)w1bT + (size_t)tile * 32768 + byte) =
            f2b(w1b[(size_t)(kh * 128 + kk) * 640 + nc * 128 + c]);
        return;
    }
    t -= 163840;
    if (t < 65536) { int n = t >> 8, k = t & 255; w2aT[t] = f2b(w2a[k * 256 + n]); return; }
    t -= 65536;
    if (t < 32768) { int n = t >> 8, k = t & 255; w2bT[t] = f2b(w2b[k * 128 + n]); return; }
}

__global__ void scan_kernel(const int* __restrict__ cnt, int* __restrict__ rowptr, int O) {
    __shared__ int sc[1024];
    const int tid = threadIdx.x;
    const int per = (O + 1023) >> 10;
    const int base = tid * per;
    int s = 0;
    for (int i = 0; i < per; ++i) { int j = base + i; if (j < O) s += cnt[j]; }
    sc[tid] = s;
    __syncthreads();
    for (int d = 1; d < 1024; d <<= 1) {
        int v = (tid >= d) ? sc[tid - d] : 0;
        __syncthreads();
        sc[tid] += v;
        __syncthreads();
    }
    int off = sc[tid] - s;
    for (int i = 0; i < per; ++i) {
        int j = base + i;
        if (j < O) { rowptr[j] = off; off += cnt[j]; }
    }
    if (tid == 0) rowptr[O] = sc[1023];
}

// ---------------- edge MLP: round-16 version (BM=128, 512 thr, 160KB LDS) ----------------
__global__ __launch_bounds__(512, 2) void edge_mlp(
    const float* __restrict__ obj, const float* __restrict__ pred,
    const int* __restrict__ edges,
    const unsigned short* __restrict__ w1aT, const float* __restrict__ b1a,
    const unsigned short* __restrict__ w1bT, const float* __restrict__ b1b,
    const int* __restrict__ slotS, const int* __restrict__ slotO,
    const int* __restrict__ rowptr,
    unsigned short* __restrict__ edgeout, float* __restrict__ outP, int T) {
    const int m0 = blockIdx.x * 128;
    const int tid = threadIdx.x;
    const int lane = tid & 63, wid = tid >> 6;
    const int wm = wid >> 2, wn = wid & 3;
    const bool evenL = ((lane & 1) == 0);

    __shared__ unsigned short U[81920];
    char* const ldsb = (char*)U;
    char* const bbase = ldsb + 65536;

    bool okR[4][4];
    #pragma unroll
    for (int mi = 0; mi < 4; ++mi)
        #pragma unroll
        for (int rr = 0; rr < 4; ++rr)
            okR[mi][rr] = (m0 + wm * 64 + mi * 16 + ((lane >> 4) << 2) + rr) < T;

    int slotSr[4][2], slotOr[4][2];
    #pragma unroll
    for (int mi = 0; mi < 4; ++mi)
        #pragma unroll
        for (int k = 0; k < 2; ++k) {
            int rsel = evenL ? k : 2 + k;
            int e = m0 + wm * 64 + mi * 16 + ((lane >> 4) << 2) + rsel;
            if (e >= T) e = T - 1;
            int si = edges[2 * (long long)e];
            int oi = edges[2 * (long long)e + 1];
            slotSr[mi][k] = slotS[e] + rowptr[si];
            slotOr[mi][k] = slotO[e] + rowptr[oi];
        }

    const int r = tid >> 2;
    const int q = tid & 3;
    int e_r = m0 + r; if (e_r >= T) e_r = T - 1;
    const int sIdx_r = edges[2 * (long long)e_r];
    const int oIdx_r = edges[2 * (long long)e_r + 1];

    float bias1[4], bias2[5][2];
    #pragma unroll
    for (int nj = 0; nj < 4; ++nj) bias1[nj] = b1a[wn * 64 + nj * 16 + (lane & 15)];
    #pragma unroll
    for (int nc = 0; nc < 5; ++nc)
        #pragma unroll
        for (int nj = 0; nj < 2; ++nj)
            bias2[nc][nj] = b1b[nc * 128 + wn * 32 + nj * 16 + (lane & 15)];

    // force-retire ALL preamble vmem loads: clean vmcnt FIFO before the counted pipeline
    #pragma unroll
    for (int mi = 0; mi < 4; ++mi)
        #pragma unroll
        for (int k = 0; k < 2; ++k)
            asm volatile("" :: "v"(slotSr[mi][k]), "v"(slotOr[mi][k]));
    #pragma unroll
    for (int nj = 0; nj < 4; ++nj) asm volatile("" :: "v"(bias1[nj]));
    #pragma unroll
    for (int nc = 0; nc < 5; ++nc)
        #pragma unroll
        for (int nj = 0; nj < 2; ++nj) asm volatile("" :: "v"(bias2[nc][nj]));
    asm volatile("" :: "v"((float)sIdx_r), "v"((float)oIdx_r));
    SCHEDB;

    auto aSrc = [&](int kt) -> const float4* {
        const float* s;
        if (kt < 2)      s = obj  + (long long)sIdx_r * 128 + kt * 64;
        else if (kt < 4) s = pred + (long long)e_r   * 128 + (kt - 2) * 64;
        else             s = obj  + (long long)oIdx_r * 128 + (kt - 4) * 64;
        return (const float4*)s;
    };

    auto tp = [&](int i) -> const unsigned short* {
        return (i < 6) ? (w1aT + (size_t)i * 16384) : (w1bT + (size_t)(i - 6) * 16384);
    };

    auto stage32 = [&](const unsigned short* gt, char* bb) {
        #pragma unroll
        for (int rr4 = 0; rr4 < 4; ++rr4) {
            unsigned off = wid * 4096u + rr4 * 1024u;
            gload_lds16((const unsigned short*)((const char*)gt + off + lane * 16u),
                        (unsigned short*)(bb + off));
        }
    };

    auto writeA = [&](const float4* ap, char* ab) {
        #pragma unroll
        for (int i = 0; i < 4; ++i) {
            float4 v = ap[i];
            uint2 pk;
            pk.x = f2bpk(v.x, v.y);
            pk.y = f2bpk(v.z, v.w);
            unsigned byte = (r * 128u + q * 32u + i * 8u) ^ ((r & 7u) << 4);
            *(uint2*)(ab + byte) = pk;
        }
    };

    f32x4 acc1[4][4];
    #pragma unroll
    for (int a = 0; a < 4; ++a)
        #pragma unroll
        for (int b = 0; b < 4; ++b) acc1[a][b] = f32x4{0.f, 0.f, 0.f, 0.f};

    auto mfma1 = [&](const char* ab, const char* bb) {
        #pragma unroll
        for (int ks = 0; ks < 2; ++ks) {
            const unsigned kk = ks * 32u + ((lane >> 4) << 3);
            s16x8 af[4];
            #pragma unroll
            for (int mi = 0; mi < 4; ++mi) {
                unsigned row = wm * 64u + mi * 16u + (lane & 15);
                af[mi] = *(const s16x8*)(ab + ((row * 128u + kk * 2u) ^ ((row & 7u) << 4)));
            }
            #pragma unroll
            for (int nj = 0; nj < 4; ++nj) {
                unsigned c = wn * 64u + nj * 16u + (lane & 15);
                s16x8 bf = *(const s16x8*)(bb + ((c * 128u + kk * 2u) ^ ((c & 7u) << 4)));
                #pragma unroll
                for (int mi = 0; mi < 4; ++mi)
                    acc1[mi][nj] = __builtin_amdgcn_mfma_f32_16x16x32_bf16(af[mi], bf, acc1[mi][nj], 0, 0, 0);
            }
        }
    };

    // ---- prologue ----
    float4 ap[4];
    {
        const float4* s4 = aSrc(0);
        #pragma unroll
        for (int i = 0; i < 4; ++i) ap[i] = s4[q * 4 + i];
    }
    writeA(ap, ldsb);
    stage32(tp(0), bbase);
    stage32(tp(1), bbase + 32768);
    {
        const float4* s4 = aSrc(1);
        #pragma unroll
        for (int i = 0; i < 4; ++i) ap[i] = s4[q * 4 + i];
    }
    VMCNT8;
    LGKM0; BAR; SCHEDB;

    // ---- GEMM1 stages s=0..5 ----
    #pragma unroll
    for (int s = 0; s < 6; ++s) {
        stage32(tp(s + 2), bbase + ((s + 2) % 3) * 32768);
        __builtin_amdgcn_s_setprio(1);
        mfma1(ldsb + ((s >> 0) & 1) * 16384, bbase + (s % 3) * 32768);
        __builtin_amdgcn_s_setprio(0);
        VMCNT4;
        if (s < 5) {
            writeA(ap, ldsb + ((s + 1) & 1) * 16384);
            if (s < 4) {
                const float4* s4 = aSrc(s + 2);
                #pragma unroll
                for (int i = 0; i < 4; ++i) ap[i] = s4[q * 4 + i];
            }
        }
        LGKM0; BAR; SCHEDB;
    }

    // ---- transition: H write (cvt_pk pairs over rr) ----
    #pragma unroll
    for (int nj = 0; nj < 4; ++nj) {
        unsigned col = wn * 64u + nj * 16u + (lane & 15);
        #pragma unroll
        for (int mi = 0; mi < 4; ++mi) {
            float r0 = fmaxf(acc1[mi][nj][0] + bias1[nj], 0.f);
            float r1 = fmaxf(acc1[mi][nj][1] + bias1[nj], 0.f);
            float r2 = fmaxf(acc1[mi][nj][2] + bias1[nj], 0.f);
            float r3 = fmaxf(acc1[mi][nj][3] + bias1[nj], 0.f);
            unsigned p01 = f2bpk(r0, r1);
            unsigned p23 = f2bpk(r2, r3);
            unsigned rowb = wm * 64u + mi * 16u + ((lane >> 4) << 2);
            *(unsigned short*)(ldsb + ((rowb * 512u + col * 2u) ^ ((rowb & 7u) << 4))) = (unsigned short)p01;
            *(unsigned short*)(ldsb + (((rowb + 1) * 512u + col * 2u) ^ (((rowb + 1) & 7u) << 4))) = (unsigned short)(p01 >> 16);
            *(unsigned short*)(ldsb + (((rowb + 2) * 512u + col * 2u) ^ (((rowb + 2) & 7u) << 4))) = (unsigned short)p23;
            *(unsigned short*)(ldsb + (((rowb + 3) * 512u + col * 2u) ^ (((rowb + 3) & 7u) << 4))) = (unsigned short)(p23 >> 16);
        }
    }
    LGKM0; BAR; SCHEDB;

    // ---- GEMM2 stages s=6..15 ----
    #pragma unroll
    for (int nc = 0; nc < 5; ++nc) {
        f32x4 acc2[4][2];
        #pragma unroll
        for (int a = 0; a < 4; ++a)
            #pragma unroll
            for (int b = 0; b < 2; ++b) acc2[a][b] = f32x4{0.f, 0.f, 0.f, 0.f};

        #pragma unroll
        for (int kh = 0; kh < 2; ++kh) {
            const int s = 6 + nc * 2 + kh;
            if (s + 2 <= 15) stage32(tp(s + 2), bbase + ((s + 2) % 3) * 32768);
            const char* bb = bbase + (s % 3) * 32768;
            __builtin_amdgcn_s_setprio(1);
            #pragma unroll
            for (int ks = 0; ks < 4; ++ks) {
                const unsigned kkB = ks * 32u + ((lane >> 4) << 3);
                const unsigned kkH = (kh * 128u) + kkB;
                s16x8 af[4];
                #pragma unroll
                for (int mi = 0; mi < 4; ++mi) {
                    unsigned row = wm * 64u + mi * 16u + (lane & 15);
                    af[mi] = *(const s16x8*)(ldsb + ((row * 512u + kkH * 2u) ^ ((row & 7u) << 4)));
                }
                #pragma unroll
                for (int nj = 0; nj < 2; ++nj) {
                    unsigned c = wn * 32u + nj * 16u + (lane & 15);
                    s16x8 bf = *(const s16x8*)(bb + ((c * 256u + kkB * 2u) ^ ((c & 7u) << 4)));
                    #pragma unroll
                    for (int mi = 0; mi < 4; ++mi)
                        acc2[mi][nj] = __builtin_amdgcn_mfma_f32_16x16x32_bf16(af[mi], bf, acc2[mi][nj], 0, 0, 0);
                }
            }
            __builtin_amdgcn_s_setprio(0);

            if (kh == 0) {
                if (s == 6)       { VMCNT4; }
                else if (s == 12) { VMCNT36; }
                else if (s == 14) { VMCNT16; }
                else              { VMCNT20; }
                LGKM0; BAR; SCHEDB;
            }
        }

        if (nc == 2) {
            #pragma unroll
            for (int nj = 0; nj < 2; ++nj) {
                int col = 2 * 128 + wn * 32 + nj * 16 + (lane & 15);
                #pragma unroll
                for (int mi = 0; mi < 4; ++mi)
                    #pragma unroll
                    for (int rr = 0; rr < 4; ++rr) {
                        int row = wm * 64 + mi * 16 + ((lane >> 4) << 2) + rr;
                        if (okR[mi][rr]) {
                            float v = acc2[mi][nj][rr] + bias2[2][nj];
                            v = v > 0.f ? v : 0.f;
                            outP[(long long)(m0 + row) * 128 + (col - 256)] = v;
                        }
                    }
            }
            VMCNT36;
            LGKM0; BAR; SCHEDB;
        } else {
            #pragma unroll
            for (int nj = 0; nj < 2; ++nj) {
                int col = nc * 128 + wn * 32 + nj * 16 + (lane & 15);
                int pc = (nc < 2) ? col : (col - 384);
                int pcb = (lane & 1) ? (pc - 1) : pc;
                #pragma unroll
                for (int mi = 0; mi < 4; ++mi) {
                    float vv[4];
                    #pragma unroll
                    for (int rr = 0; rr < 4; ++rr) {
                        float v = acc2[mi][nj][rr] + bias2[nc][nj];
                        vv[rr] = v > 0.f ? v : 0.f;
                    }
                    float nb0 = __shfl_xor(vv[0], 1);
                    float nb1 = __shfl_xor(vv[1], 1);
                    float nb2 = __shfl_xor(vv[2], 1);
                    float nb3 = __shfl_xor(vv[3], 1);
                    #pragma unroll
                    for (int k = 0; k < 2; ++k) {
                        float lo = evenL ? (k ? vv[1] : vv[0]) : (k ? nb3 : nb2);
                        float hi = evenL ? (k ? nb1 : nb0) : (k ? vv[3] : vv[2]);
                        int rsel = evenL ? k : 2 + k;
                        if (okR[mi][rsel]) {
                            int slot = (nc < 2) ? slotSr[mi][k] : slotOr[mi][k];
                            unsigned pk = f2bpk(lo, hi);
                            *(unsigned*)(edgeout + (size_t)slot * 256 + pcb) = pk;
                        }
                    }
                }
            }
            if (nc < 4) {
                VMCNT20;
                LGKM0; BAR; SCHEDB;
            }
        }
    }
}

// ---------------- object MLP: paired 16B CSR gather + fused GEMMs ----------------
__global__ __launch_bounds__(256, 3) void obj_mlp(
    const unsigned short* __restrict__ edgeout, const int* __restrict__ rowptr,
    const unsigned short* __restrict__ w2aT, const float* __restrict__ b2a,
    const unsigned short* __restrict__ w2bT, const float* __restrict__ b2b,
    float* __restrict__ outObj, int O) {
    const int m0 = blockIdx.x * 64;
    const int tid = threadIdx.x;
    const int lane = tid & 63, wid = tid >> 6;
    const int wm = wid >> 1, wn = wid & 1;

    __shared__ unsigned short Abuf[64 * 256];

    // paired gather: wave reads 2 contiguous rows (1024B) per load round;
    // lane half 0 accumulates even rows, half 1 odd rows; one shfl_xor(32) combine.
    const int half = lane >> 5;
    const int coll = (lane & 31) * 8;     // 8-column slice base
    for (int it = 0; it < 16; ++it) {
        const int row = it * 4 + wid;
        const int oI = m0 + row;
        float a0 = 0.f, a1 = 0.f, a2 = 0.f, a3 = 0.f, a4 = 0.f, a5 = 0.f, a6 = 0.f, a7 = 0.f;
        int n = 0;
        if (oI < O) {
            const int beg = rowptr[oI];
            n = rowptr[oI + 1] - beg;
            const unsigned short* base = edgeout + (size_t)beg * 256 + half * 256 + coll;
            int i = 0;
            for (; i + 7 < n; i += 8) {   // 4 pairs in flight, 16B/lane each
                u16x8 v0 = *(const u16x8*)(base + (size_t)(i    ) * 256);
                u16x8 v1 = *(const u16x8*)(base + (size_t)(i + 2) * 256);
                u16x8 v2 = *(const u16x8*)(base + (size_t)(i + 4) * 256);
                u16x8 v3 = *(const u16x8*)(base + (size_t)(i + 6) * 256);
                a0 += b2f(v0[0]) + b2f(v1[0]) + b2f(v2[0]) + b2f(v3[0]);
                a1 += b2f(v0[1]) + b2f(v1[1]) + b2f(v2[1]) + b2f(v3[1]);
                a2 += b2f(v0[2]) + b2f(v1[2]) + b2f(v2[2]) + b2f(v3[2]);
                a3 += b2f(v0[3]) + b2f(v1[3]) + b2f(v2[3]) + b2f(v3[3]);
                a4 += b2f(v0[4]) + b2f(v1[4]) + b2f(v2[4]) + b2f(v3[4]);
                a5 += b2f(v0[5]) + b2f(v1[5]) + b2f(v2[5]) + b2f(v3[5]);
                a6 += b2f(v0[6]) + b2f(v1[6]) + b2f(v2[6]) + b2f(v3[6]);
                a7 += b2f(v0[7]) + b2f(v1[7]) + b2f(v2[7]) + b2f(v3[7]);
            }
            for (; i + 1 < n; i += 2) {
                u16x8 v0 = *(const u16x8*)(base + (size_t)i * 256);
                a0 += b2f(v0[0]); a1 += b2f(v0[1]); a2 += b2f(v0[2]); a3 += b2f(v0[3]);
                a4 += b2f(v0[4]); a5 += b2f(v0[5]); a6 += b2f(v0[6]); a7 += b2f(v0[7]);
            }
            if (i < n && half == 0) {     // odd leftover row: half-0 lanes read it
                u16x8 v0 = *(const u16x8*)(edgeout + (size_t)(beg + i) * 256 + coll);
                a0 += b2f(v0[0]); a1 += b2f(v0[1]); a2 += b2f(v0[2]); a3 += b2f(v0[3]);
                a4 += b2f(v0[4]); a5 += b2f(v0[5]); a6 += b2f(v0[6]); a7 += b2f(v0[7]);
            }
        }
        a0 += __shfl_xor(a0, 32); a1 += __shfl_xor(a1, 32);
        a2 += __shfl_xor(a2, 32); a3 += __shfl_xor(a3, 32);
        a4 += __shfl_xor(a4, 32); a5 += __shfl_xor(a5, 32);
        a6 += __shfl_xor(a6, 32); a7 += __shfl_xor(a7, 32);
        float inv = 1.f / fmaxf((float)n, 1.f);
        if (half == 0) {
            uint4 pk4;
            pk4.x = f2bpk(a0 * inv, a1 * inv);
            pk4.y = f2bpk(a2 * inv, a3 * inv);
            pk4.z = f2bpk(a4 * inv, a5 * inv);
            pk4.w = f2bpk(a6 * inv, a7 * inv);
            unsigned byte = ((unsigned)row * 512u + (unsigned)coll * 2u) ^ (((unsigned)row & 7u) << 4);
            *(uint4*)((char*)Abuf + byte) = pk4;   // oI>=O -> zeros
        }
    }
    __syncthreads();

    f32x4 acc1[2][2][4];
    #pragma unroll
    for (int a = 0; a < 2; ++a)
        #pragma unroll
        for (int b = 0; b < 2; ++b)
            #pragma unroll
            for (int c = 0; c < 4; ++c) acc1[a][b][c] = f32x4{0.f, 0.f, 0.f, 0.f};
    #pragma unroll
    for (int ks = 0; ks < 8; ++ks) {
        const int klane = ks * 32 + ((lane >> 4) << 3);
        s16x8 af[2];
        #pragma unroll
        for (int mi = 0; mi < 2; ++mi) {
            int row = wm * 32 + mi * 16 + (lane & 15);
            af[mi] = *(const s16x8*)((const char*)Abuf + swz(row, row * 512u + klane * 2u));
        }
        #pragma unroll
        for (int nb = 0; nb < 2; ++nb)
            #pragma unroll
            for (int nj = 0; nj < 4; ++nj) {
                int col = nb * 128 + wn * 64 + nj * 16 + (lane & 15);
                s16x8 bf = *(const s16x8*)(w2aT + (long long)col * 256 + klane);
                #pragma unroll
                for (int mi = 0; mi < 2; ++mi)
                    acc1[nb][mi][nj] = __builtin_amdgcn_mfma_f32_16x16x32_bf16(af[mi], bf, acc1[nb][mi][nj], 0, 0, 0);
            }
    }
    __syncthreads();

    #pragma unroll
    for (int nb = 0; nb < 2; ++nb)
        #pragma unroll
        for (int nj = 0; nj < 4; ++nj) {
            int col = nb * 128 + wn * 64 + nj * 16 + (lane & 15);
            float bias = b2a[col];
            #pragma unroll
            for (int mi = 0; mi < 2; ++mi) {
                float r0 = fmaxf(acc1[nb][mi][nj][0] + bias, 0.f);
                float r1 = fmaxf(acc1[nb][mi][nj][1] + bias, 0.f);
                float r2 = fmaxf(acc1[nb][mi][nj][2] + bias, 0.f);
                float r3 = fmaxf(acc1[nb][mi][nj][3] + bias, 0.f);
                unsigned p01 = f2bpk(r0, r1);
                unsigned p23 = f2bpk(r2, r3);
                int rowb = wm * 32 + mi * 16 + ((lane >> 4) << 2);
                *(unsigned short*)((char*)Abuf + swz(rowb, rowb * 512u + col * 2u)) = (unsigned short)p01;
                *(unsigned short*)((char*)Abuf + swz(rowb + 1, (rowb + 1) * 512u + col * 2u)) = (unsigned short)(p01 >> 16);
                *(unsigned short*)((char*)Abuf + swz(rowb + 2, (rowb + 2) * 512u + col * 2u)) = (unsigned short)p23;
                *(unsigned short*)((char*)Abuf + swz(rowb + 3, (rowb + 3) * 512u + col * 2u)) = (unsigned short)(p23 >> 16);
            }
        }
    __syncthreads();

    f32x4 acc2[2][4];
    #pragma unroll
    for (int b = 0; b < 2; ++b)
        #pragma unroll
        for (int c = 0; c < 4; ++c) acc2[b][c] = f32x4{0.f, 0.f, 0.f, 0.f};
    #pragma unroll
    for (int ks = 0; ks < 8; ++ks) {
        const int klane = ks * 32 + ((lane >> 4) << 3);
        s16x8 af[2];
        #pragma unroll
        for (int mi = 0; mi < 2; ++mi) {
            int row = wm * 32 + mi * 16 + (lane & 15);
            af[mi] = *(const s16x8*)((const char*)Abuf + swz(row, row * 512u + klane * 2u));
        }
        #pragma unroll
        for (int nj = 0; nj < 4; ++nj) {
            int col = wn * 64 + nj * 16 + (lane & 15);
            s16x8 bf = *(const s16x8*)(w2bT + (long long)col * 256 + klane);
            #pragma unroll
            for (int mi = 0; mi < 2; ++mi)
                acc2[mi][nj] = __builtin_amdgcn_mfma_f32_16x16x32_bf16(af[mi], bf, acc2[mi][nj], 0, 0, 0);
        }
    }

    #pragma unroll
    for (int nj = 0; nj < 4; ++nj) {
        int col = wn * 64 + nj * 16 + (lane & 15);
        float bias = b2b[col];
        #pragma unroll
        for (int mi = 0; mi < 2; ++mi)
            #pragma unroll
            for (int rr = 0; rr < 4; ++rr) {
                int row = wm * 32 + mi * 16 + ((lane >> 4) << 2) + rr;
                int o = m0 + row;
                if (o < O) {
                    float v = acc2[mi][nj][rr] + bias;
                    v = v > 0.f ? v : 0.f;
                    outObj[(long long)o * 128 + col] = v;
                }
            }
    }
}

extern "C" void kernel_launch(void* const* d_in, const int* in_sizes, int n_in,
                              void* d_out, int out_size, void* d_ws, size_t ws_size,
                              hipStream_t stream) {
    const float* obj  = (const float*)d_in[0];
    const float* pred = (const float*)d_in[1];
    const int*   edges = (const int*)d_in[2];
    const float* w1a = (const float*)d_in[3];
    const float* b1a = (const float*)d_in[4];
    const float* w1b = (const float*)d_in[5];
    const float* b1b = (const float*)d_in[6];
    const float* w2a = (const float*)d_in[7];
    const float* b2a = (const float*)d_in[8];
    const float* w2b = (const float*)d_in[9];
    const float* b2b = (const float*)d_in[10];

    const int O = in_sizes[0] / 128;
    const int T = in_sizes[1] / 128;

    auto al = [](size_t x) { return (x + 255) & ~(size_t)255; };
    const size_t szEdgeout = (size_t)2 * T * 256 * 2;
    const size_t szCnt     = (size_t)O * 4;
    const size_t szRow     = (size_t)(O + 1) * 4;
    const size_t szSlot    = (size_t)T * 4;

    size_t off = 0;
    char* ws = (char*)d_ws;
    unsigned short* edgeout = (unsigned short*)(ws + off); off += al(szEdgeout);
    int* cnt    = (int*)(ws + off); off += al(szCnt);
    int* rowptr = (int*)(ws + off); off += al(szRow);
    int* slotS  = (int*)(ws + off); off += al(szSlot);
    int* slotO  = (int*)(ws + off); off += al(szSlot);
    unsigned short* w1aT = (unsigned short*)(ws + off); off += (size_t)6 * 16384 * 2;
    unsigned short* w1bT = (unsigned short*)(ws + off); off += (size_t)10 * 16384 * 2;
    unsigned short* w2aT = (unsigned short*)(ws + off); off += (size_t)256 * 256 * 2;
    unsigned short* w2bT = (unsigned short*)(ws + off);

    float* outObj = (float*)d_out;
    float* outP   = (float*)d_out + (size_t)O * 128;

    hipMemsetAsync(cnt, 0, szCnt, stream);
    const int totalT = PREP_ELEMS + T;
    prep_count_kernel<<<(totalT + 255) / 256, 256, 0, stream>>>(
        w1a, w1b, w2a, w2b, w1aT, w1bT, w2aT, w2bT, edges, cnt, slotS, slotO, T);
    scan_kernel<<<1, 1024, 0, stream>>>(cnt, rowptr, O);
    edge_mlp<<<(T + 127) / 128, 512, 0, stream>>>(obj, pred, edges, w1aT, b1a, w1bT, b1b,
                                                  slotS, slotO, rowptr, edgeout, outP, T);
    obj_mlp<<<(O + 63) / 64, 256, 0, stream>>>(edgeout, rowptr, w2aT, b2a, w2bT, b2b, outObj, O);
}

// Round 20
// 832.557 us; speedup vs baseline: 1.0701x; 1.0426x over previous
//
#include <hip/hip_runtime.h>

// GraphConv: edge MLP (384->256->640, bf16 MFMA) + slot-direct CSR pool + obj MLP (256->256->128)
// Round 20: gather UN-FUSED from obj_mlp. Standalone pool_gather (no LDS, launch_bounds(256,8),
// 32 waves/CU) gets enough loads in flight to run the contiguous 512MB read at HBM BW; obj_mlp
// reverts to cheap pooled staging. edge_mlp byte-identical to round 19 (555us control).

using f32x4 = __attribute__((ext_vector_type(4))) float;
using s16x8 = __attribute__((ext_vector_type(8))) short;
typedef unsigned short u16x8 __attribute__((ext_vector_type(8)));

#define VMCNT4  asm volatile("s_waitcnt vmcnt(4)" ::: "memory")
#define VMCNT8  asm volatile("s_waitcnt vmcnt(8)" ::: "memory")
#define VMCNT16 asm volatile("s_waitcnt vmcnt(16)" ::: "memory")
#define VMCNT20 asm volatile("s_waitcnt vmcnt(20)" ::: "memory")
#define VMCNT36 asm volatile("s_waitcnt vmcnt(36)" ::: "memory")
#define LGKM0   asm volatile("s_waitcnt lgkmcnt(0)" ::: "memory")
#define BAR     __builtin_amdgcn_s_barrier()
#define SCHEDB  __builtin_amdgcn_sched_barrier(0)

static __device__ __forceinline__ unsigned short f2b(float f) {
    unsigned int u = __float_as_uint(f);
    unsigned int r = (u + 0x7fffu + ((u >> 16) & 1u)) >> 16;  // RNE f32->bf16
    return (unsigned short)r;
}

static __device__ __forceinline__ unsigned f2bpk(float lo, float hi) {
    unsigned r;
    asm("v_cvt_pk_bf16_f32 %0, %1, %2" : "=v"(r) : "v"(lo), "v"(hi));
    return r;
}

static __device__ __forceinline__ float b2f(unsigned short b) {
    return __uint_as_float(((unsigned)b) << 16);
}

static __device__ __forceinline__ unsigned swz(unsigned row, unsigned byteoff) {
    return byteoff ^ ((row & 7u) << 4);
}

static __device__ __forceinline__ void gload_lds16(const unsigned short* g, unsigned short* l) {
    __builtin_amdgcn_global_load_lds(
        (const __attribute__((address_space(1))) unsigned int*)g,
        (__attribute__((address_space(3))) unsigned int*)l,
        16, 0, 0);
}

#define PREP_ELEMS (98304 + 163840 + 65536 + 32768)   // 360448

// ---------------- fused weight prep + CSR count/slot (round-16 tiling) ----------------
__global__ void prep_count_kernel(const float* __restrict__ w1a, const float* __restrict__ w1b,
                                  const float* __restrict__ w2a, const float* __restrict__ w2b,
                                  unsigned short* __restrict__ w1aT, unsigned short* __restrict__ w1bT,
                                  unsigned short* __restrict__ w2aT, unsigned short* __restrict__ w2bT,
                                  const int* __restrict__ edges, int* __restrict__ cnt,
                                  int* __restrict__ slotS, int* __restrict__ slotO, int T) {
    int t = blockIdx.x * blockDim.x + threadIdx.x;
    if (t >= PREP_ELEMS) {
        int e = t - PREP_ELEMS;
        if (e < T) {
            slotS[e] = atomicAdd(&cnt[edges[2 * (long long)e]], 1);
            slotO[e] = atomicAdd(&cnt[edges[2 * (long long)e + 1]], 1);
        }
        return;
    }
    if (t < 6 * 16384) {
        int kt = t >> 14;
        int rem = t & 16383; int c = rem >> 6, kk = rem & 63;
        unsigned byte = ((unsigned)(c * 128 + kk * 2)) ^ ((c & 7u) << 4);
        *(unsigned short*)((char*)w1aT + (size_t)kt * 32768 + byte) =
            f2b(w1a[(size_t)(kt * 64 + kk) * 256 + c]);
        return;
    }
    t -= 98304;
    if (t < 10 * 16384) {
        int tile = t >> 14; int nc = tile >> 1, kh = tile & 1;
        int rem = t & 16383; int c = rem >> 7, kk = rem & 127;
        unsigned byte = ((unsigned)(c * 256 + kk * 2)) ^ ((c & 7u) << 4);
        *(unsigned short*)((char*)w1bT + (size_t)tile * 32768 + byte) =
            f2b(w1b[(size_t)(kh * 128 + kk) * 640 + nc * 128 + c]);
        return;
    }
    t -= 163840;
    if (t < 65536) { int n = t >> 8, k = t & 255; w2aT[t] = f2b(w2a[k * 256 + n]); return; }
    t -= 65536;
    if (t < 32768) { int n = t >> 8, k = t & 255; w2bT[t] = f2b(w2b[k * 128 + n]); return; }
}

__global__ void scan_kernel(const int* __restrict__ cnt, int* __restrict__ rowptr, int O) {
    __shared__ int sc[1024];
    const int tid = threadIdx.x;
    const int per = (O + 1023) >> 10;
    const int base = tid * per;
    int s = 0;
    for (int i = 0; i < per; ++i) { int j = base + i; if (j < O) s += cnt[j]; }
    sc[tid] = s;
    __syncthreads();
    for (int d = 1; d < 1024; d <<= 1) {
        int v = (tid >= d) ? sc[tid - d] : 0;
        __syncthreads();
        sc[tid] += v;
        __syncthreads();
    }
    int off = sc[tid] - s;
    for (int i = 0; i < per; ++i) {
        int j = base + i;
        if (j < O) { rowptr[j] = off; off += cnt[j]; }
    }
    if (tid == 0) rowptr[O] = sc[1023];
}

// ---------------- edge MLP: round-16/19 version (BM=128, 512 thr, 160KB LDS) ----------------
__global__ __launch_bounds__(512, 2) void edge_mlp(
    const float* __restrict__ obj, const float* __restrict__ pred,
    const int* __restrict__ edges,
    const unsigned short* __restrict__ w1aT, const float* __restrict__ b1a,
    const unsigned short* __restrict__ w1bT, const float* __restrict__ b1b,
    const int* __restrict__ slotS, const int* __restrict__ slotO,
    const int* __restrict__ rowptr,
    unsigned short* __restrict__ edgeout, float* __restrict__ outP, int T) {
    const int m0 = blockIdx.x * 128;
    const int tid = threadIdx.x;
    const int lane = tid & 63, wid = tid >> 6;
    const int wm = wid >> 2, wn = wid & 3;
    const bool evenL = ((lane & 1) == 0);

    __shared__ unsigned short U[81920];
    char* const ldsb = (char*)U;
    char* const bbase = ldsb + 65536;

    bool okR[4][4];
    #pragma unroll
    for (int mi = 0; mi < 4; ++mi)
        #pragma unroll
        for (int rr = 0; rr < 4; ++rr)
            okR[mi][rr] = (m0 + wm * 64 + mi * 16 + ((lane >> 4) << 2) + rr) < T;

    int slotSr[4][2], slotOr[4][2];
    #pragma unroll
    for (int mi = 0; mi < 4; ++mi)
        #pragma unroll
        for (int k = 0; k < 2; ++k) {
            int rsel = evenL ? k : 2 + k;
            int e = m0 + wm * 64 + mi * 16 + ((lane >> 4) << 2) + rsel;
            if (e >= T) e = T - 1;
            int si = edges[2 * (long long)e];
            int oi = edges[2 * (long long)e + 1];
            slotSr[mi][k] = slotS[e] + rowptr[si];
            slotOr[mi][k] = slotO[e] + rowptr[oi];
        }

    const int r = tid >> 2;
    const int q = tid & 3;
    int e_r = m0 + r; if (e_r >= T) e_r = T - 1;
    const int sIdx_r = edges[2 * (long long)e_r];
    const int oIdx_r = edges[2 * (long long)e_r + 1];

    float bias1[4], bias2[5][2];
    #pragma unroll
    for (int nj = 0; nj < 4; ++nj) bias1[nj] = b1a[wn * 64 + nj * 16 + (lane & 15)];
    #pragma unroll
    for (int nc = 0; nc < 5; ++nc)
        #pragma unroll
        for (int nj = 0; nj < 2; ++nj)
            bias2[nc][nj] = b1b[nc * 128 + wn * 32 + nj * 16 + (lane & 15)];

    // force-retire ALL preamble vmem loads: clean vmcnt FIFO before the counted pipeline
    #pragma unroll
    for (int mi = 0; mi < 4; ++mi)
        #pragma unroll
        for (int k = 0; k < 2; ++k)
            asm volatile("" :: "v"(slotSr[mi][k]), "v"(slotOr[mi][k]));
    #pragma unroll
    for (int nj = 0; nj < 4; ++nj) asm volatile("" :: "v"(bias1[nj]));
    #pragma unroll
    for (int nc = 0; nc < 5; ++nc)
        #pragma unroll
        for (int nj = 0; nj < 2; ++nj) asm volatile("" :: "v"(bias2[nc][nj]));
    asm volatile("" :: "v"((float)sIdx_r), "v"((float)oIdx_r));
    SCHEDB;

    auto aSrc = [&](int kt) -> const float4* {
        const float* s;
        if (kt < 2)      s = obj  + (long long)sIdx_r * 128 + kt * 64;
        else if (kt < 4) s = pred + (long long)e_r   * 128 + (kt - 2) * 64;
        else             s = obj  + (long long)oIdx_r * 128 + (kt - 4) * 64;
        return (const float4*)s;
    };

    auto tp = [&](int i) -> const unsigned short* {
        return (i < 6) ? (w1aT + (size_t)i * 16384) : (w1bT + (size_t)(i - 6) * 16384);
    };

    auto stage32 = [&](const unsigned short* gt, char* bb) {
        #pragma unroll
        for (int rr4 = 0; rr4 < 4; ++rr4) {
            unsigned off = wid * 4096u + rr4 * 1024u;
            gload_lds16((const unsigned short*)((const char*)gt + off + lane * 16u),
                        (unsigned short*)(bb + off));
        }
    };

    auto writeA = [&](const float4* ap, char* ab) {
        #pragma unroll
        for (int i = 0; i < 4; ++i) {
            float4 v = ap[i];
            uint2 pk;
            pk.x = f2bpk(v.x, v.y);
            pk.y = f2bpk(v.z, v.w);
            unsigned byte = (r * 128u + q * 32u + i * 8u) ^ ((r & 7u) << 4);
            *(uint2*)(ab + byte) = pk;
        }
    };

    f32x4 acc1[4][4];
    #pragma unroll
    for (int a = 0; a < 4; ++a)
        #pragma unroll
        for (int b = 0; b < 4; ++b) acc1[a][b] = f32x4{0.f, 0.f, 0.f, 0.f};

    auto mfma1 = [&](const char* ab, const char* bb) {
        #pragma unroll
        for (int ks = 0; ks < 2; ++ks) {
            const unsigned kk = ks * 32u + ((lane >> 4) << 3);
            s16x8 af[4];
            #pragma unroll
            for (int mi = 0; mi < 4; ++mi) {
                unsigned row = wm * 64u + mi * 16u + (lane & 15);
                af[mi] = *(const s16x8*)(ab + ((row * 128u + kk * 2u) ^ ((row & 7u) << 4)));
            }
            #pragma unroll
            for (int nj = 0; nj < 4; ++nj) {
                unsigned c = wn * 64u + nj * 16u + (lane & 15);
                s16x8 bf = *(const s16x8*)(bb + ((c * 128u + kk * 2u) ^ ((c & 7u) << 4)));
                #pragma unroll
                for (int mi = 0; mi < 4; ++mi)
                    acc1[mi][nj] = __builtin_amdgcn_mfma_f32_16x16x32_bf16(af[mi], bf, acc1[mi][nj], 0, 0, 0);
            }
        }
    };

    // ---- prologue ----
    float4 ap[4];
    {
        const float4* s4 = aSrc(0);
        #pragma unroll
        for (int i = 0; i < 4; ++i) ap[i] = s4[q * 4 + i];
    }
    writeA(ap, ldsb);
    stage32(tp(0), bbase);
    stage32(tp(1), bbase + 32768);
    {
        const float4* s4 = aSrc(1);
        #pragma unroll
        for (int i = 0; i < 4; ++i) ap[i] = s4[q * 4 + i];
    }
    VMCNT8;
    LGKM0; BAR; SCHEDB;

    // ---- GEMM1 stages s=0..5 ----
    #pragma unroll
    for (int s = 0; s < 6; ++s) {
        stage32(tp(s + 2), bbase + ((s + 2) % 3) * 32768);
        __builtin_amdgcn_s_setprio(1);
        mfma1(ldsb + (s & 1) * 16384, bbase + (s % 3) * 32768);
        __builtin_amdgcn_s_setprio(0);
        VMCNT4;
        if (s < 5) {
            writeA(ap, ldsb + ((s + 1) & 1) * 16384);
            if (s < 4) {
                const float4* s4 = aSrc(s + 2);
                #pragma unroll
                for (int i = 0; i < 4; ++i) ap[i] = s4[q * 4 + i];
            }
        }
        LGKM0; BAR; SCHEDB;
    }

    // ---- transition: H write (cvt_pk pairs over rr) ----
    #pragma unroll
    for (int nj = 0; nj < 4; ++nj) {
        unsigned col = wn * 64u + nj * 16u + (lane & 15);
        #pragma unroll
        for (int mi = 0; mi < 4; ++mi) {
            float r0 = fmaxf(acc1[mi][nj][0] + bias1[nj], 0.f);
            float r1 = fmaxf(acc1[mi][nj][1] + bias1[nj], 0.f);
            float r2 = fmaxf(acc1[mi][nj][2] + bias1[nj], 0.f);
            float r3 = fmaxf(acc1[mi][nj][3] + bias1[nj], 0.f);
            unsigned p01 = f2bpk(r0, r1);
            unsigned p23 = f2bpk(r2, r3);
            unsigned rowb = wm * 64u + mi * 16u + ((lane >> 4) << 2);
            *(unsigned short*)(ldsb + ((rowb * 512u + col * 2u) ^ ((rowb & 7u) << 4))) = (unsigned short)p01;
            *(unsigned short*)(ldsb + (((rowb + 1) * 512u + col * 2u) ^ (((rowb + 1) & 7u) << 4))) = (unsigned short)(p01 >> 16);
            *(unsigned short*)(ldsb + (((rowb + 2) * 512u + col * 2u) ^ (((rowb + 2) & 7u) << 4))) = (unsigned short)p23;
            *(unsigned short*)(ldsb + (((rowb + 3) * 512u + col * 2u) ^ (((rowb + 3) & 7u) << 4))) = (unsigned short)(p23 >> 16);
        }
    }
    LGKM0; BAR; SCHEDB;

    // ---- GEMM2 stages s=6..15 ----
    #pragma unroll
    for (int nc = 0; nc < 5; ++nc) {
        f32x4 acc2[4][2];
        #pragma unroll
        for (int a = 0; a < 4; ++a)
            #pragma unroll
            for (int b = 0; b < 2; ++b) acc2[a][b] = f32x4{0.f, 0.f, 0.f, 0.f};

        #pragma unroll
        for (int kh = 0; kh < 2; ++kh) {
            const int s = 6 + nc * 2 + kh;
            if (s + 2 <= 15) stage32(tp(s + 2), bbase + ((s + 2) % 3) * 32768);
            const char* bb = bbase + (s % 3) * 32768;
            __builtin_amdgcn_s_setprio(1);
            #pragma unroll
            for (int ks = 0; ks < 4; ++ks) {
                const unsigned kkB = ks * 32u + ((lane >> 4) << 3);
                const unsigned kkH = (kh * 128u) + kkB;
                s16x8 af[4];
                #pragma unroll
                for (int mi = 0; mi < 4; ++mi) {
                    unsigned row = wm * 64u + mi * 16u + (lane & 15);
                    af[mi] = *(const s16x8*)(ldsb + ((row * 512u + kkH * 2u) ^ ((row & 7u) << 4)));
                }
                #pragma unroll
                for (int nj = 0; nj < 2; ++nj) {
                    unsigned c = wn * 32u + nj * 16u + (lane & 15);
                    s16x8 bf = *(const s16x8*)(bb + ((c * 256u + kkB * 2u) ^ ((c & 7u) << 4)));
                    #pragma unroll
                    for (int mi = 0; mi < 4; ++mi)
                        acc2[mi][nj] = __builtin_amdgcn_mfma_f32_16x16x32_bf16(af[mi], bf, acc2[mi][nj], 0, 0, 0);
                }
            }
            __builtin_amdgcn_s_setprio(0);

            if (kh == 0) {
                if (s == 6)       { VMCNT4; }
                else if (s == 12) { VMCNT36; }
                else if (s == 14) { VMCNT16; }
                else              { VMCNT20; }
                LGKM0; BAR; SCHEDB;
            }
        }

        if (nc == 2) {
            #pragma unroll
            for (int nj = 0; nj < 2; ++nj) {
                int col = 2 * 128 + wn * 32 + nj * 16 + (lane & 15);
                #pragma unroll
                for (int mi = 0; mi < 4; ++mi)
                    #pragma unroll
                    for (int rr = 0; rr < 4; ++rr) {
                        int row = wm * 64 + mi * 16 + ((lane >> 4) << 2) + rr;
                        if (okR[mi][rr]) {
                            float v = acc2[mi][nj][rr] + bias2[2][nj];
                            v = v > 0.f ? v : 0.f;
                            outP[(long long)(m0 + row) * 128 + (col - 256)] = v;
                        }
                    }
            }
            VMCNT36;
            LGKM0; BAR; SCHEDB;
        } else {
            #pragma unroll
            for (int nj = 0; nj < 2; ++nj) {
                int col = nc * 128 + wn * 32 + nj * 16 + (lane & 15);
                int pc = (nc < 2) ? col : (col - 384);
                int pcb = (lane & 1) ? (pc - 1) : pc;
                #pragma unroll
                for (int mi = 0; mi < 4; ++mi) {
                    float vv[4];
                    #pragma unroll
                    for (int rr = 0; rr < 4; ++rr) {
                        float v = acc2[mi][nj][rr] + bias2[nc][nj];
                        vv[rr] = v > 0.f ? v : 0.f;
                    }
                    float nb0 = __shfl_xor(vv[0], 1);
                    float nb1 = __shfl_xor(vv[1], 1);
                    float nb2 = __shfl_xor(vv[2], 1);
                    float nb3 = __shfl_xor(vv[3], 1);
                    #pragma unroll
                    for (int k = 0; k < 2; ++k) {
                        float lo = evenL ? (k ? vv[1] : vv[0]) : (k ? nb3 : nb2);
                        float hi = evenL ? (k ? nb1 : nb0) : (k ? vv[3] : vv[2]);
                        int rsel = evenL ? k : 2 + k;
                        if (okR[mi][rsel]) {
                            int slot = (nc < 2) ? slotSr[mi][k] : slotOr[mi][k];
                            unsigned pk = f2bpk(lo, hi);
                            *(unsigned*)(edgeout + (size_t)slot * 256 + pcb) = pk;
                        }
                    }
                }
            }
            if (nc < 4) {
                VMCNT20;
                LGKM0; BAR; SCHEDB;
            }
        }
    }
}

// ---------------- standalone pool_gather: no LDS, 32 waves/CU, paired 16B loads ----------------
__global__ __launch_bounds__(256, 8) void pool_gather(
    const unsigned short* __restrict__ edgeout, const int* __restrict__ rowptr,
    unsigned short* __restrict__ pooled, int O) {
    const int w = blockIdx.x * 4 + (threadIdx.x >> 6);   // one wave per object
    if (w >= O) return;
    const int lane = threadIdx.x & 63;
    const int half = lane >> 5;
    const int coll = (lane & 31) * 8;

    const int beg = rowptr[w];
    const int n = rowptr[w + 1] - beg;
    float a0 = 0.f, a1 = 0.f, a2 = 0.f, a3 = 0.f, a4 = 0.f, a5 = 0.f, a6 = 0.f, a7 = 0.f;
    const unsigned short* base = edgeout + (size_t)beg * 256 + half * 256 + coll;
    int i = 0;
    for (; i + 7 < n; i += 8) {     // 4 paired rows in flight, 16B/lane
        u16x8 v0 = *(const u16x8*)(base + (size_t)(i    ) * 256);
        u16x8 v1 = *(const u16x8*)(base + (size_t)(i + 2) * 256);
        u16x8 v2 = *(const u16x8*)(base + (size_t)(i + 4) * 256);
        u16x8 v3 = *(const u16x8*)(base + (size_t)(i + 6) * 256);
        a0 += b2f(v0[0]) + b2f(v1[0]) + b2f(v2[0]) + b2f(v3[0]);
        a1 += b2f(v0[1]) + b2f(v1[1]) + b2f(v2[1]) + b2f(v3[1]);
        a2 += b2f(v0[2]) + b2f(v1[2]) + b2f(v2[2]) + b2f(v3[2]);
        a3 += b2f(v0[3]) + b2f(v1[3]) + b2f(v2[3]) + b2f(v3[3]);
        a4 += b2f(v0[4]) + b2f(v1[4]) + b2f(v2[4]) + b2f(v3[4]);
        a5 += b2f(v0[5]) + b2f(v1[5]) + b2f(v2[5]) + b2f(v3[5]);
        a6 += b2f(v0[6]) + b2f(v1[6]) + b2f(v2[6]) + b2f(v3[6]);
        a7 += b2f(v0[7]) + b2f(v1[7]) + b2f(v2[7]) + b2f(v3[7]);
    }
    for (; i + 1 < n; i += 2) {
        u16x8 v0 = *(const u16x8*)(base + (size_t)i * 256);
        a0 += b2f(v0[0]); a1 += b2f(v0[1]); a2 += b2f(v0[2]); a3 += b2f(v0[3]);
        a4 += b2f(v0[4]); a5 += b2f(v0[5]); a6 += b2f(v0[6]); a7 += b2f(v0[7]);
    }
    if (i < n && half == 0) {       // odd leftover row
        u16x8 v0 = *(const u16x8*)(edgeout + (size_t)(beg + i) * 256 + coll);
        a0 += b2f(v0[0]); a1 += b2f(v0[1]); a2 += b2f(v0[2]); a3 += b2f(v0[3]);
        a4 += b2f(v0[4]); a5 += b2f(v0[5]); a6 += b2f(v0[6]); a7 += b2f(v0[7]);
    }
    a0 += __shfl_xor(a0, 32); a1 += __shfl_xor(a1, 32);
    a2 += __shfl_xor(a2, 32); a3 += __shfl_xor(a3, 32);
    a4 += __shfl_xor(a4, 32); a5 += __shfl_xor(a5, 32);
    a6 += __shfl_xor(a6, 32); a7 += __shfl_xor(a7, 32);
    float inv = 1.f / fmaxf((float)n, 1.f);
    if (half == 0) {
        uint4 pk4;
        pk4.x = f2bpk(a0 * inv, a1 * inv);
        pk4.y = f2bpk(a2 * inv, a3 * inv);
        pk4.z = f2bpk(a4 * inv, a5 * inv);
        pk4.w = f2bpk(a6 * inv, a7 * inv);
        *(uint4*)(pooled + (size_t)w * 256 + coll) = pk4;   // 32 lanes x 16B = 512B row
    }
}

// ---------------- object MLP: cheap pooled staging + fused GEMMs ----------------
__global__ __launch_bounds__(256, 3) void obj_mlp(
    const unsigned short* __restrict__ pooled,
    const unsigned short* __restrict__ w2aT, const float* __restrict__ b2a,
    const unsigned short* __restrict__ w2bT, const float* __restrict__ b2b,
    float* __restrict__ outObj, int O) {
    const int m0 = blockIdx.x * 64;
    const int tid = threadIdx.x;
    const int lane = tid & 63, wid = tid >> 6;
    const int wm = wid >> 1, wn = wid & 1;

    __shared__ unsigned short Abuf[64 * 256];

    {
        const int r = tid >> 2, q = tid & 3;
        int objc = m0 + r; if (objc >= O) objc = O - 1;
        const u16x8* s8 = (const u16x8*)(pooled + (size_t)objc * 256);
        #pragma unroll
        for (int i = 0; i < 8; ++i) {
            u16x8 v = s8[q * 8 + i];
            unsigned byte = r * 512u + (q * 64u + i * 8u) * 2u;
            *(u16x8*)((char*)Abuf + swz(r, byte)) = v;
        }
    }
    __syncthreads();

    f32x4 acc1[2][2][4];
    #pragma unroll
    for (int a = 0; a < 2; ++a)
        #pragma unroll
        for (int b = 0; b < 2; ++b)
            #pragma unroll
            for (int c = 0; c < 4; ++c) acc1[a][b][c] = f32x4{0.f, 0.f, 0.f, 0.f};
    #pragma unroll
    for (int ks = 0; ks < 8; ++ks) {
        const int klane = ks * 32 + ((lane >> 4) << 3);
        s16x8 af[2];
        #pragma unroll
        for (int mi = 0; mi < 2; ++mi) {
            int row = wm * 32 + mi * 16 + (lane & 15);
            af[mi] = *(const s16x8*)((const char*)Abuf + swz(row, row * 512u + klane * 2u));
        }
        #pragma unroll
        for (int nb = 0; nb < 2; ++nb)
            #pragma unroll
            for (int nj = 0; nj < 4; ++nj) {
                int col = nb * 128 + wn * 64 + nj * 16 + (lane & 15);
                s16x8 bf = *(const s16x8*)(w2aT + (long long)col * 256 + klane);
                #pragma unroll
                for (int mi = 0; mi < 2; ++mi)
                    acc1[nb][mi][nj] = __builtin_amdgcn_mfma_f32_16x16x32_bf16(af[mi], bf, acc1[nb][mi][nj], 0, 0, 0);
            }
    }
    __syncthreads();

    #pragma unroll
    for (int nb = 0; nb < 2; ++nb)
        #pragma unroll
        for (int nj = 0; nj < 4; ++nj) {
            int col = nb * 128 + wn * 64 + nj * 16 + (lane & 15);
            float bias = b2a[col];
            #pragma unroll
            for (int mi = 0; mi < 2; ++mi) {
                float r0 = fmaxf(acc1[nb][mi][nj][0] + bias, 0.f);
                float r1 = fmaxf(acc1[nb][mi][nj][1] + bias, 0.f);
                float r2 = fmaxf(acc1[nb][mi][nj][2] + bias, 0.f);
                float r3 = fmaxf(acc1[nb][mi][nj][3] + bias, 0.f);
                unsigned p01 = f2bpk(r0, r1);
                unsigned p23 = f2bpk(r2, r3);
                int rowb = wm * 32 + mi * 16 + ((lane >> 4) << 2);
                *(unsigned short*)((char*)Abuf + swz(rowb, rowb * 512u + col * 2u)) = (unsigned short)p01;
                *(unsigned short*)((char*)Abuf + swz(rowb + 1, (rowb + 1) * 512u + col * 2u)) = (unsigned short)(p01 >> 16);
                *(unsigned short*)((char*)Abuf + swz(rowb + 2, (rowb + 2) * 512u + col * 2u)) = (unsigned short)p23;
                *(unsigned short*)((char*)Abuf + swz(rowb + 3, (rowb + 3) * 512u + col * 2u)) = (unsigned short)(p23 >> 16);
            }
        }
    __syncthreads();

    f32x4 acc2[2][4];
    #pragma unroll
    for (int b = 0; b < 2; ++b)
        #pragma unroll
        for (int c = 0; c < 4; ++c) acc2[b][c] = f32x4{0.f, 0.f, 0.f, 0.f};
    #pragma unroll
    for (int ks = 0; ks < 8; ++ks) {
        const int klane = ks * 32 + ((lane >> 4) << 3);
        s16x8 af[2];
        #pragma unroll
        for (int mi = 0; mi < 2; ++mi) {
            int row = wm * 32 + mi * 16 + (lane & 15);
            af[mi] = *(const s16x8*)((const char*)Abuf + swz(row, row * 512u + klane * 2u));
        }
        #pragma unroll
        for (int nj = 0; nj < 4; ++nj) {
            int col = wn * 64 + nj * 16 + (lane & 15);
            s16x8 bf = *(const s16x8*)(w2bT + (long long)col * 256 + klane);
            #pragma unroll
            for (int mi = 0; mi < 2; ++mi)
                acc2[mi][nj] = __builtin_amdgcn_mfma_f32_16x16x32_bf16(af[mi], bf, acc2[mi][nj], 0, 0, 0);
        }
    }

    #pragma unroll
    for (int nj = 0; nj < 4; ++nj) {
        int col = wn * 64 + nj * 16 + (lane & 15);
        float bias = b2b[col];
        #pragma unroll
        for (int mi = 0; mi < 2; ++mi)
            #pragma unroll
            for (int rr = 0; rr < 4; ++rr) {
                int row = wm * 32 + mi * 16 + ((lane >> 4) << 2) + rr;
                int o = m0 + row;
                if (o < O) {
                    float v = acc2[mi][nj][rr] + bias;
                    v = v > 0.f ? v : 0.f;
                    outObj[(long long)o * 128 + col] = v;
                }
            }
    }
}

extern "C" void kernel_launch(void* const* d_in, const int* in_sizes, int n_in,
                              void* d_out, int out_size, void* d_ws, size_t ws_size,
                              hipStream_t stream) {
    const float* obj  = (const float*)d_in[0];
    const float* pred = (const float*)d_in[1];
    const int*   edges = (const int*)d_in[2];
    const float* w1a = (const float*)d_in[3];
    const float* b1a = (const float*)d_in[4];
    const float* w1b = (const float*)d_in[5];
    const float* b1b = (const float*)d_in[6];
    const float* w2a = (const float*)d_in[7];
    const float* b2a = (const float*)d_in[8];
    const float* w2b = (const float*)d_in[9];
    const float* b2b = (const float*)d_in[10];

    const int O = in_sizes[0] / 128;
    const int T = in_sizes[1] / 128;

    auto al = [](size_t x) { return (x + 255) & ~(size_t)255; };
    const size_t szEdgeout = (size_t)2 * T * 256 * 2;
    const size_t szPooled  = (size_t)O * 256 * 2;
    const size_t szCnt     = (size_t)O * 4;
    const size_t szRow     = (size_t)(O + 1) * 4;
    const size_t szSlot    = (size_t)T * 4;

    size_t off = 0;
    char* ws = (char*)d_ws;
    unsigned short* edgeout = (unsigned short*)(ws + off); off += al(szEdgeout);
    unsigned short* pooled  = (unsigned short*)(ws + off); off += al(szPooled);
    int* cnt    = (int*)(ws + off); off += al(szCnt);
    int* rowptr = (int*)(ws + off); off += al(szRow);
    int* slotS  = (int*)(ws + off); off += al(szSlot);
    int* slotO  = (int*)(ws + off); off += al(szSlot);
    unsigned short* w1aT = (unsigned short*)(ws + off); off += (size_t)6 * 16384 * 2;
    unsigned short* w1bT = (unsigned short*)(ws + off); off += (size_t)10 * 16384 * 2;
    unsigned short* w2aT = (unsigned short*)(ws + off); off += (size_t)256 * 256 * 2;
    unsigned short* w2bT = (unsigned short*)(ws + off);

    float* outObj = (float*)d_out;
    float* outP   = (float*)d_out + (size_t)O * 128;

    hipMemsetAsync(cnt, 0, szCnt, stream);
    const int totalT = PREP_ELEMS + T;
    prep_count_kernel<<<(totalT + 255) / 256, 256, 0, stream>>>(
        w1a, w1b, w2a, w2b, w1aT, w1bT, w2aT, w2bT, edges, cnt, slotS, slotO, T);
    scan_kernel<<<1, 1024, 0, stream>>>(cnt, rowptr, O);
    edge_mlp<<<(T + 127) / 128, 512, 0, stream>>>(obj, pred, edges, w1aT, b1a, w1bT, b1b,
                                                  slotS, slotO, rowptr, edgeout, outP, T);
    pool_gather<<<(O + 3) / 4, 256, 0, stream>>>(edgeout, rowptr, pooled, O);
    obj_mlp<<<(O + 63) / 64, 256, 0, stream>>>(pooled, w2aT, b2a, w2bT, b2b, outObj, O);
}